// Round 10
// baseline (406.186 us; speedup 1.0000x reference)
//
#include <hip/hip_runtime.h>
#include <stdint.h>

#define D 256

typedef __attribute__((ext_vector_type(8))) short bf16x8;
typedef __attribute__((ext_vector_type(4))) float f32x4;

__device__ inline unsigned short f2bf(float f) {
    union { float f; uint32_t u; } v; v.f = f;
    return (unsigned short)((v.u + 0x7FFFu + ((v.u >> 16) & 1u)) >> 16);
}
__device__ inline float bf2f(unsigned short b) {
    return __uint_as_float(((uint32_t)b) << 16);
}

// segment geometry (padded to 1024-multiples for the block scan)
#define SEG0 0
#define SEG1 50176
#define SEG2 62464
#define CURTOT 66560          // 50176+12288+4096
#define NBLK 65               // seg0 blocks 0-48, seg1 49-60, seg2 61-64

#define WBLK 1536             // 6*65536/256

// ---------- fused preprocessing: weights (PERMUTED) + edge count -------------
// wt layout per W (65536 shorts): tile (nb,kt) = 4096 shorts (512 chunks x 8).
// chunk c: g=c>>6, q=(c>>4)&3, cl=c&15 -> col = nb*128+g*16+cl, k = kt*32+q*8+j.
// GEMM Bs staging is linear; bfr ds_reads are canonical (conflict-free).
struct PreArgs {
    const float* w[6];
    unsigned short* wt;
    const int* d0; const int* d1; const int* d2;
    int* cur;
    int E0, E01, Etot;
};

__global__ __launch_bounds__(256) void fused_pre(PreArgs a)
{
    int b = blockIdx.x;
    if (b < WBLK) {
        int t = b * 256 + threadIdx.x;
        int m = t >> 16, e = t & 65535;
        int tile = e >> 12;            // nb*8 + kt
        int nb = tile >> 3, kt = tile & 7;
        int cc = (e >> 3) & 511;
        int j  = e & 7;
        int g = cc >> 6, q = (cc >> 4) & 3, cl = cc & 15;
        int col = nb * 128 + g * 16 + cl;
        int k   = kt * 32 + q * 8 + j;
        a.wt[t] = f2bf(a.w[m][k * 256 + col]);
    } else {
        int e = (b - WBLK) * 256 + threadIdx.x;
        if (e >= a.Etot) return;
        int base, d;
        if (e < a.E0)       { base = SEG0; d = a.d0[e]; }
        else if (e < a.E01) { base = SEG1; d = a.d1[e - a.E0]; }
        else                { base = SEG2; d = a.d2[e - a.E01]; }
        atomicAdd(&a.cur[base + d], 1);
    }
}

// ---------- single-pass segmented scan with decoupled lookback ---------------
__global__ __launch_bounds__(256) void scan_lookback(
    int* __restrict__ cur, unsigned int* __restrict__ flag)
{
    __shared__ int wsum[4];
    __shared__ int sprefix;
    int tid = threadIdx.x, lane = tid & 63, wid = tid >> 6;
    int b = blockIdx.x;
    int base = b * 1024 + tid * 4;
    int4 v = *(int4*)(cur + base);
    int t0 = v.x, t01 = t0 + v.y, t012 = t01 + v.z, tot = t012 + v.w;
    int incl = tot;
    #pragma unroll
    for (int ofs = 1; ofs < 64; ofs <<= 1) {
        int t = __shfl_up(incl, ofs, 64);
        if (lane >= ofs) incl += t;
    }
    if (lane == 63) wsum[wid] = incl;
    __syncthreads();
    if (tid == 0) {
        int run = 0;
        #pragma unroll
        for (int w = 0; w < 4; ++w) { int t = wsum[w]; wsum[w] = run; run += t; }
        int segfirst = (b >= 61) ? 61 : (b >= 49) ? 49 : 0;
        int pfx = 0;
        if (b != segfirst) {
            unsigned int f;
            do {
                f = __hip_atomic_load(&flag[b - 1], __ATOMIC_ACQUIRE,
                                      __HIP_MEMORY_SCOPE_AGENT);
            } while (f == 0);
            pfx = (int)(f - 1u);
        }
        __hip_atomic_store(&flag[b], (unsigned int)(pfx + run) + 1u,
                           __ATOMIC_RELEASE, __HIP_MEMORY_SCOPE_AGENT);
        sprefix = pfx;
    }
    __syncthreads();
    int add = sprefix + wsum[wid] + incl - tot;
    v.x = add; v.y = add + t0; v.z = add + t01; v.w = add + t012;
    *(int4*)(cur + base) = v;
}

// fill: idx[cursor(dst)] = src; afterwards cur[] holds INCLUSIVE offsets
__global__ __launch_bounds__(256) void fill_all(
    const int* __restrict__ s0, const int* __restrict__ s1, const int* __restrict__ s2,
    const int* __restrict__ d0, const int* __restrict__ d1, const int* __restrict__ d2,
    int* __restrict__ cur, int* __restrict__ idx, int E0, int E01, int Etot)
{
    int e = blockIdx.x * 256 + threadIdx.x;
    if (e >= Etot) return;
    int base, d, s, ib;
    if (e < E0)       { base = SEG0; d = d0[e];       s = s0[e];       ib = 0; }
    else if (e < E01) { base = SEG1; d = d1[e - E0];  s = s1[e - E0];  ib = E0; }
    else              { base = SEG2; d = d2[e - E01]; s = s2[e - E01]; ib = E01; }
    int p = atomicAdd(&cur[base + d], 1);
    idx[ib + p] = s;
}

// ---------- fused layer: block gathers its 128 rows' means, then GEMM --------
// 512 threads = 8 waves (2 row-halves x 4 col-quarters), tile 128x256, K=512.
// Gather: wave wid handles rows [m0+wid*16, +16), full-row access like the
// proven standalone gather (lane covers 16B fp32 / 8B bf16 of the row).
// Mean rows stored bf16 to this block's PRIVATE meanb slice; phase-2 A-staging
// re-reads them via global_load_lds (same-block L2, drained by kt-0 barrier).
template<int FINAL, int F32>
__global__ __launch_bounds__(512) void sage_fused(
    const void* __restrict__ hv,
    const int* __restrict__ idx,
    const int* __restrict__ curseg,
    const unsigned short* __restrict__ Wt1,
    const unsigned short* __restrict__ Wt2,
    const float* __restrict__ bias,
    unsigned short* __restrict__ meanb,
    void* __restrict__ outv,
    int M)
{
    __shared__ unsigned short As[128 * 32];   //  8 KB
    __shared__ unsigned short Bs[256 * 32];   // 16 KB (two permuted 128-col tiles)

    int tid = threadIdx.x;
    int lane = tid & 63, wid = tid >> 6;
    int wr = wid >> 2, wc = wid & 3;          // 2 x 4 waves
    int m0 = blockIdx.x * 128;
    int l15 = lane & 15, lq = lane >> 4;

    // ---- block-local gather+mean: 8 waves x 16 rows ----
    {
        int rowbase = m0 + wid * 16;
        for (int r = 0; r < 16; ++r) {
            int w = rowbase + r;
            if (w >= M) break;
            int e0 = w ? curseg[w - 1] : 0;
            int e1 = curseg[w];
            float4 a0 = make_float4(0.f, 0.f, 0.f, 0.f);
            float4 a1 = make_float4(0.f, 0.f, 0.f, 0.f);
            int e = e0;
            if (F32) {
                const float* h = (const float*)hv;
                for (; e + 1 < e1; e += 2) {
                    int sa = idx[e], sb = idx[e + 1];
                    float4 va = *((const float4*)(h + (size_t)sa * D) + lane);
                    float4 vb = *((const float4*)(h + (size_t)sb * D) + lane);
                    a0.x += va.x; a0.y += va.y; a0.z += va.z; a0.w += va.w;
                    a1.x += vb.x; a1.y += vb.y; a1.z += vb.z; a1.w += vb.w;
                }
                if (e < e1) {
                    float4 va = *((const float4*)(h + (size_t)idx[e] * D) + lane);
                    a0.x += va.x; a0.y += va.y; a0.z += va.z; a0.w += va.w;
                }
            } else {
                const unsigned short* h = (const unsigned short*)hv;
                for (; e + 1 < e1; e += 2) {
                    int sa = idx[e], sb = idx[e + 1];
                    ushort4 va = *(const ushort4*)(h + (size_t)sa * D + lane * 4);
                    ushort4 vb = *(const ushort4*)(h + (size_t)sb * D + lane * 4);
                    a0.x += bf2f(va.x); a0.y += bf2f(va.y);
                    a0.z += bf2f(va.z); a0.w += bf2f(va.w);
                    a1.x += bf2f(vb.x); a1.y += bf2f(vb.y);
                    a1.z += bf2f(vb.z); a1.w += bf2f(vb.w);
                }
                if (e < e1) {
                    ushort4 va = *(const ushort4*)((const unsigned short*)hv +
                                                   (size_t)idx[e] * D + lane * 4);
                    a0.x += bf2f(va.x); a0.y += bf2f(va.y);
                    a0.z += bf2f(va.z); a0.w += bf2f(va.w);
                }
            }
            a0.x += a1.x; a0.y += a1.y; a0.z += a1.z; a0.w += a1.w;
            float rd = 1.0f / fmaxf((float)(e1 - e0), 1.0f);
            ushort4 o;
            o.x = f2bf(a0.x * rd); o.y = f2bf(a0.y * rd);
            o.z = f2bf(a0.z * rd); o.w = f2bf(a0.w * rd);
            if (F32) {
                // fp32 rows: lane covers floats [lane*4, lane*4+4) -> bf16 8B
                *(ushort4*)(meanb + (size_t)w * D + lane * 4) = o;
            } else {
                *(ushort4*)(meanb + (size_t)w * D + lane * 4) = o;
            }
        }
    }
    // no barrier needed here: first __syncthreads below covers it (with vmcnt drain)

    f32x4 acc[4][4] = {};

    for (int kt = 0; kt < 16; ++kt) {
        int kk = (kt & 7) * 32;
        // ---- A tile 128x32 (8 KB): 512 chunks of 16B, 1/thread ----
        if (kt < 8) {
            if (F32) {
                const float* A = (const float*)hv;
                int r = tid >> 2, c16 = tid & 3;
                int gr = m0 + r; if (gr >= M) gr = M - 1;
                const float* s = A + (size_t)gr * 256 + kk + c16 * 8;
                float4 u0 = *(const float4*)s;
                float4 u1 = *(const float4*)(s + 4);
                unsigned short rr[8] = {f2bf(u0.x), f2bf(u0.y), f2bf(u0.z), f2bf(u0.w),
                                        f2bf(u1.x), f2bf(u1.y), f2bf(u1.z), f2bf(u1.w)};
                *(uint4*)(As + tid * 8) = *(uint4*)rr;
            } else {
                const unsigned short* A = (const unsigned short*)hv;
                int r = tid >> 2, c16 = tid & 3;
                int gr = m0 + r; if (gr >= M) gr = M - 1;
                const unsigned short* s = A + (size_t)gr * 256 + kk + c16 * 8;
                __builtin_amdgcn_global_load_lds(
                    (const __attribute__((address_space(1))) void*)s,
                    (__attribute__((address_space(3))) void*)(As + tid * 8),
                    16, 0, 0);
            }
        } else {
            int r = tid >> 2, c16 = tid & 3;
            int gr = m0 + r; if (gr >= M) gr = M - 1;
            const unsigned short* s = meanb + (size_t)gr * 256 + kk + c16 * 8;
            __builtin_amdgcn_global_load_lds(
                (const __attribute__((address_space(1))) void*)s,
                (__attribute__((address_space(3))) void*)(As + tid * 8),
                16, 0, 0);
        }
        // ---- B tiles (16 KB): linear staging from pre-permuted wt ----
        {
            const unsigned short* B = (kt < 8) ? Wt1 : Wt2;
            #pragma unroll
            for (int q = 0; q < 2; ++q) {
                const unsigned short* tb = B + (size_t)(q * 8 + (kt & 7)) * 4096;
                __builtin_amdgcn_global_load_lds(
                    (const __attribute__((address_space(1))) void*)(tb + tid * 8),
                    (__attribute__((address_space(3))) void*)(Bs + (q * 512 + tid) * 8),
                    16, 0, 0);
            }
        }
        __syncthreads();

        bf16x8 af[4], bfr[4];
        int th = wc >> 1;                     // tile half (cols 0-127 / 128-255)
        #pragma unroll
        for (int i = 0; i < 4; ++i) {
            af[i]  = *(const bf16x8*)(As + (wr * 64 + i * 16 + l15) * 32 + lq * 8);
            bfr[i] = *(const bf16x8*)(Bs + th * 4096 +
                                      (((wc & 1) * 4 + i) * 64 + lane) * 8);
        }
        #pragma unroll
        for (int mr = 0; mr < 4; ++mr)
            #pragma unroll
            for (int nc = 0; nc < 4; ++nc)
                acc[mr][nc] = __builtin_amdgcn_mfma_f32_16x16x32_bf16(
                    af[mr], bfr[nc], acc[mr][nc], 0, 0, 0);
        __syncthreads();
    }

    // epilogue: bias + relu; C/D layout col=lane&15, row=(lane>>4)*4+reg
    #pragma unroll
    for (int nc = 0; nc < 4; ++nc) {
        int gc = wc * 64 + nc * 16 + l15;
        float bv = bias[gc];
        #pragma unroll
        for (int mr = 0; mr < 4; ++mr) {
            #pragma unroll
            for (int reg = 0; reg < 4; ++reg) {
                int gr = m0 + wr * 64 + mr * 16 + lq * 4 + reg;
                if (gr < M) {
                    float v = fmaxf(acc[mr][nc][reg] + bv, 0.f);
                    if (FINAL) ((float*)outv)[(size_t)gr * 256 + gc] = v;
                    else ((unsigned short*)outv)[(size_t)gr * 256 + gc] = f2bf(v);
                }
            }
        }
    }
}

extern "C" void kernel_launch(void* const* d_in, const int* in_sizes, int n_in,
                              void* d_out, int out_size, void* d_ws, size_t ws_size,
                              hipStream_t stream) {
    const float* x = (const float*)d_in[0];
    const float* Wself[3]  = {(const float*)d_in[1], (const float*)d_in[4], (const float*)d_in[7]};
    const float* Wneigh[3] = {(const float*)d_in[2], (const float*)d_in[5], (const float*)d_in[8]};
    const float* bias[3]   = {(const float*)d_in[3], (const float*)d_in[6], (const float*)d_in[9]};
    const int* src[3] = {(const int*)d_in[10], (const int*)d_in[12], (const int*)d_in[14]};
    const int* dst[3] = {(const int*)d_in[11], (const int*)d_in[13], (const int*)d_in[15]};
    int E[3]    = {in_sizes[10], in_sizes[12], in_sizes[14]};
    int E0 = E[0], E01 = E[0] + E[1], Etot = E[0] + E[1] + E[2];

    // workspace
    unsigned short* h1b = (unsigned short*)d_ws;            // 50000*256
    unsigned short* h2b = h1b + (size_t)50000 * D;          // 12000*256
    unsigned short* meanb = h2b + (size_t)12000 * D;        // 50000*256
    unsigned short* wt  = meanb + (size_t)50000 * D;        // 6*65536 permuted
    int* cur            = (int*)(wt + 6 * 65536);           // CURTOT
    unsigned int* flag  = (unsigned int*)(cur + CURTOT);    // NBLK (pad 80)
    int* idxa           = (int*)(flag + 80);                // Etot (<=660000)

    hipMemsetAsync(cur, 0, (CURTOT + 80) * sizeof(int), stream);

    PreArgs pa;
    pa.w[0] = Wself[0]; pa.w[1] = Wneigh[0];
    pa.w[2] = Wself[1]; pa.w[3] = Wneigh[1];
    pa.w[4] = Wself[2]; pa.w[5] = Wneigh[2];
    pa.wt = wt;
    pa.d0 = dst[0]; pa.d1 = dst[1]; pa.d2 = dst[2];
    pa.cur = cur; pa.E0 = E0; pa.E01 = E01; pa.Etot = Etot;
    int cblk = (Etot + 255) / 256;
    fused_pre<<<WBLK + cblk, 256, 0, stream>>>(pa);

    scan_lookback<<<NBLK, 256, 0, stream>>>(cur, flag);

    fill_all<<<(Etot + 255) / 256, 256, 0, stream>>>(src[0], src[1], src[2],
        dst[0], dst[1], dst[2], cur, idxa, E0, E01, Etot);

    sage_fused<0, 1><<<(50000 + 127) / 128, 512, 0, stream>>>(
        x, idxa + 0, cur + SEG0, wt + 0 * 65536, wt + 1 * 65536,
        bias[0], meanb, h1b, 50000);
    sage_fused<0, 0><<<(12000 + 127) / 128, 512, 0, stream>>>(
        h1b, idxa + E0, cur + SEG1, wt + 2 * 65536, wt + 3 * 65536,
        bias[1], meanb, h2b, 12000);
    sage_fused<1, 0><<<(4000 + 127) / 128, 512, 0, stream>>>(
        h2b, idxa + E01, cur + SEG2, wt + 4 * 65536, wt + 5 * 65536,
        bias[2], meanb, d_out, 4000);
}

// Round 11
// 314.505 us; speedup vs baseline: 1.2915x; 1.2915x over previous
//
#include <hip/hip_runtime.h>
#include <hip/hip_cooperative_groups.h>
#include <stdint.h>

#define D 256
#define NT 512

typedef __attribute__((ext_vector_type(8))) short bf16x8;
typedef __attribute__((ext_vector_type(4))) float f32x4;

__device__ inline unsigned short f2bf(float f) {
    union { float f; uint32_t u; } v; v.f = f;
    return (unsigned short)((v.u + 0x7FFFu + ((v.u >> 16) & 1u)) >> 16);
}
__device__ inline float bf2f(unsigned short b) {
    return __uint_as_float(((uint32_t)b) << 16);
}

// segment geometry (padded to 1024-multiples for the block scan)
#define SEG0 0
#define SEG1 50176
#define SEG2 62464
#define CURTOT 66560          // 50176+12288+4096
#define NBLK 65               // seg0 blocks 0-48, seg1 49-60, seg2 61-64

struct MegaArgs {
    const float* x;
    const float* w[6];
    const float* bias0; const float* bias1; const float* bias2;
    const int* s0; const int* s1; const int* s2;
    const int* d0; const int* d1; const int* d2;
    unsigned short* wt; unsigned short* h1b; unsigned short* h2b;
    unsigned short* meanb;
    int* cur; unsigned int* flag; int* idxa;
    float* out;
    int E0, E01, Etot;
};

// ---------- gather: one wave per row, grid-stride (proven R9 access pattern) --
template<int F32>
__device__ void gather_phase(const void* __restrict__ hv,
                             const int* __restrict__ idx,
                             const int* __restrict__ curseg,
                             unsigned short* __restrict__ meanb,
                             int M, int nb, int tid)
{
    int lane = tid & 63;
    int nwaves = nb * (NT / 64);
    for (int w = blockIdx.x * (NT / 64) + (tid >> 6); w < M; w += nwaves) {
        int e0 = w ? curseg[w - 1] : 0;
        int e1 = curseg[w];
        float4 a0 = make_float4(0.f, 0.f, 0.f, 0.f);
        float4 a1 = make_float4(0.f, 0.f, 0.f, 0.f);
        int e = e0;
        if (F32) {
            const float* h = (const float*)hv;
            for (; e + 3 < e1; e += 4) {
                int sa = idx[e], sb = idx[e + 1], sc = idx[e + 2], sd = idx[e + 3];
                float4 va = *((const float4*)(h + (size_t)sa * D) + lane);
                float4 vb = *((const float4*)(h + (size_t)sb * D) + lane);
                float4 vc = *((const float4*)(h + (size_t)sc * D) + lane);
                float4 vd = *((const float4*)(h + (size_t)sd * D) + lane);
                a0.x += va.x + vb.x; a0.y += va.y + vb.y;
                a0.z += va.z + vb.z; a0.w += va.w + vb.w;
                a1.x += vc.x + vd.x; a1.y += vc.y + vd.y;
                a1.z += vc.z + vd.z; a1.w += vc.w + vd.w;
            }
            for (; e < e1; ++e) {
                float4 va = *((const float4*)(h + (size_t)idx[e] * D) + lane);
                a0.x += va.x; a0.y += va.y; a0.z += va.z; a0.w += va.w;
            }
        } else {
            const unsigned short* h = (const unsigned short*)hv;
            for (; e + 3 < e1; e += 4) {
                int sa = idx[e], sb = idx[e + 1], sc = idx[e + 2], sd = idx[e + 3];
                ushort4 va = *(const ushort4*)(h + (size_t)sa * D + lane * 4);
                ushort4 vb = *(const ushort4*)(h + (size_t)sb * D + lane * 4);
                ushort4 vc = *(const ushort4*)(h + (size_t)sc * D + lane * 4);
                ushort4 vd = *(const ushort4*)(h + (size_t)sd * D + lane * 4);
                a0.x += bf2f(va.x) + bf2f(vb.x); a0.y += bf2f(va.y) + bf2f(vb.y);
                a0.z += bf2f(va.z) + bf2f(vb.z); a0.w += bf2f(va.w) + bf2f(vb.w);
                a1.x += bf2f(vc.x) + bf2f(vd.x); a1.y += bf2f(vc.y) + bf2f(vd.y);
                a1.z += bf2f(vc.z) + bf2f(vd.z); a1.w += bf2f(vc.w) + bf2f(vd.w);
            }
            for (; e < e1; ++e) {
                ushort4 va = *(const ushort4*)((const unsigned short*)hv +
                                               (size_t)idx[e] * D + lane * 4);
                a0.x += bf2f(va.x); a0.y += bf2f(va.y);
                a0.z += bf2f(va.z); a0.w += bf2f(va.w);
            }
        }
        a0.x += a1.x; a0.y += a1.y; a0.z += a1.z; a0.w += a1.w;
        float r = 1.0f / fmaxf((float)(e1 - e0), 1.0f);
        ushort4 o;
        o.x = f2bf(a0.x * r); o.y = f2bf(a0.y * r);
        o.z = f2bf(a0.z * r); o.w = f2bf(a0.w * r);
        *(ushort4*)(meanb + (size_t)w * D + lane * 4) = o;
    }
}

// ---------- GEMM: 128x256 tile, 8 waves (2x4), grid-stride over tiles --------
// (geometry + permuted-B indexing proven in R10)
template<int FINAL, int A1F32>
__device__ void gemm_phase(const void* __restrict__ hv,
                           const unsigned short* __restrict__ meanb,
                           const unsigned short* __restrict__ Wt1,
                           const unsigned short* __restrict__ Wt2,
                           const float* __restrict__ bias,
                           void* __restrict__ outv,
                           int M, int nb, int tid,
                           unsigned short* As, unsigned short* Bs)
{
    int lane = tid & 63, wid = tid >> 6;
    int wr = wid >> 2, wc = wid & 3;
    int l15 = lane & 15, lq = lane >> 4;
    int ntiles = (M + 127) / 128;

    for (int t = blockIdx.x; t < ntiles; t += nb) {
        int m0 = t * 128;
        f32x4 acc[4][4] = {};
        for (int kt = 0; kt < 16; ++kt) {
            int kk = (kt & 7) * 32;
            // A tile 128x32 (8 KB): 512 chunks of 16B, 1/thread
            if (kt < 8) {
                if (A1F32) {
                    const float* A = (const float*)hv;
                    int r = tid >> 2, c16 = tid & 3;
                    int gr = m0 + r; if (gr >= M) gr = M - 1;
                    const float* s = A + (size_t)gr * 256 + kk + c16 * 8;
                    float4 u0 = *(const float4*)s;
                    float4 u1 = *(const float4*)(s + 4);
                    unsigned short rr[8] = {f2bf(u0.x), f2bf(u0.y), f2bf(u0.z), f2bf(u0.w),
                                            f2bf(u1.x), f2bf(u1.y), f2bf(u1.z), f2bf(u1.w)};
                    *(uint4*)(As + tid * 8) = *(uint4*)rr;
                } else {
                    const unsigned short* A = (const unsigned short*)hv;
                    int r = tid >> 2, c16 = tid & 3;
                    int gr = m0 + r; if (gr >= M) gr = M - 1;
                    const unsigned short* s = A + (size_t)gr * 256 + kk + c16 * 8;
                    __builtin_amdgcn_global_load_lds(
                        (const __attribute__((address_space(1))) void*)s,
                        (__attribute__((address_space(3))) void*)(As + tid * 8),
                        16, 0, 0);
                }
            } else {
                int r = tid >> 2, c16 = tid & 3;
                int gr = m0 + r; if (gr >= M) gr = M - 1;
                const unsigned short* s = meanb + (size_t)gr * 256 + kk + c16 * 8;
                __builtin_amdgcn_global_load_lds(
                    (const __attribute__((address_space(1))) void*)s,
                    (__attribute__((address_space(3))) void*)(As + tid * 8),
                    16, 0, 0);
            }
            // B tiles (16 KB): linear staging from pre-permuted wt
            {
                const unsigned short* B = (kt < 8) ? Wt1 : Wt2;
                #pragma unroll
                for (int q = 0; q < 2; ++q) {
                    const unsigned short* tb = B + (size_t)(q * 8 + (kt & 7)) * 4096;
                    __builtin_amdgcn_global_load_lds(
                        (const __attribute__((address_space(1))) void*)(tb + tid * 8),
                        (__attribute__((address_space(3))) void*)(Bs + (q * 512 + tid) * 8),
                        16, 0, 0);
                }
            }
            __syncthreads();

            bf16x8 af[4], bfr[4];
            int th = wc >> 1;
            #pragma unroll
            for (int i = 0; i < 4; ++i) {
                af[i]  = *(const bf16x8*)(As + (wr * 64 + i * 16 + l15) * 32 + lq * 8);
                bfr[i] = *(const bf16x8*)(Bs + th * 4096 +
                                          (((wc & 1) * 4 + i) * 64 + lane) * 8);
            }
            #pragma unroll
            for (int mr = 0; mr < 4; ++mr)
                #pragma unroll
                for (int nc = 0; nc < 4; ++nc)
                    acc[mr][nc] = __builtin_amdgcn_mfma_f32_16x16x32_bf16(
                        af[mr], bfr[nc], acc[mr][nc], 0, 0, 0);
            __syncthreads();
        }
        // epilogue: bias + relu; C/D layout col=lane&15, row=(lane>>4)*4+reg
        #pragma unroll
        for (int nc = 0; nc < 4; ++nc) {
            int gc = wc * 64 + nc * 16 + l15;
            float bv = bias[gc];
            #pragma unroll
            for (int mr = 0; mr < 4; ++mr) {
                #pragma unroll
                for (int reg = 0; reg < 4; ++reg) {
                    int gr = m0 + wr * 64 + mr * 16 + lq * 4 + reg;
                    if (gr < M) {
                        float v = fmaxf(acc[mr][nc][reg] + bv, 0.f);
                        if (FINAL) ((float*)outv)[(size_t)gr * 256 + gc] = v;
                        else ((unsigned short*)outv)[(size_t)gr * 256 + gc] = f2bf(v);
                    }
                }
            }
        }
    }
}

// ---------- the kernel: COOP=1 runs all phases with grid.sync; COOP=0 runs
// only PHASE (fallback as 10 plain launches) ----------
template<int COOP, int PHASE>
__global__ __launch_bounds__(NT) void mega(MegaArgs a)
{
    __shared__ unsigned short As[128 * 32];   //  8 KB
    __shared__ unsigned short Bs[256 * 32];   // 16 KB
    __shared__ int wsum[4];
    __shared__ int sprefix;

    int tid = threadIdx.x;
    int nb = gridDim.x;
    long gtid = (long)blockIdx.x * NT + tid;
    long nth = (long)nb * NT;

    // P0: zero cur+flag, transpose weights (permuted layout)
    if (PHASE < 0 || PHASE == 0) {
        for (long i = gtid; i < CURTOT + 80; i += nth) a.cur[i] = 0;
        for (long t = gtid; t < 6 * 65536; t += nth) {
            int m = (int)(t >> 16), e = (int)(t & 65535);
            int tile = e >> 12;
            int nb2 = tile >> 3, kt = tile & 7;
            int cc = (e >> 3) & 511, j = e & 7;
            int g = cc >> 6, q = (cc >> 4) & 3, cl = cc & 15;
            int col = nb2 * 128 + g * 16 + cl;
            int k   = kt * 32 + q * 8 + j;
            a.wt[t] = f2bf(a.w[m][k * 256 + col]);
        }
    }
    if constexpr (COOP) cooperative_groups::this_grid().sync();

    // P1: count
    if (PHASE < 0 || PHASE == 1) {
        for (long e = gtid; e < a.Etot; e += nth) {
            int base, d;
            if (e < a.E0)       { base = SEG0; d = a.d0[e]; }
            else if (e < a.E01) { base = SEG1; d = a.d1[e - a.E0]; }
            else                { base = SEG2; d = a.d2[e - a.E01]; }
            atomicAdd(&a.cur[base + d], 1);
        }
    }
    if constexpr (COOP) cooperative_groups::this_grid().sync();

    // P2: segmented scan with decoupled lookback (blocks 0..64)
    if (PHASE < 0 || PHASE == 2) {
        int b = blockIdx.x;
        if (b < NBLK) {
            int lane = tid & 63, wid = tid >> 6;
            int4 v; int t0 = 0, t01 = 0, t012 = 0, tot = 0, incl = 0;
            if (tid < 256) {
                v = *(int4*)(a.cur + b * 1024 + tid * 4);
                t0 = v.x; t01 = t0 + v.y; t012 = t01 + v.z; tot = t012 + v.w;
                incl = tot;
                #pragma unroll
                for (int ofs = 1; ofs < 64; ofs <<= 1) {
                    int t = __shfl_up(incl, ofs, 64);
                    if (lane >= ofs) incl += t;
                }
                if (lane == 63) wsum[wid] = incl;
            }
            __syncthreads();
            if (tid == 0) {
                int run = 0;
                #pragma unroll
                for (int w = 0; w < 4; ++w) { int t = wsum[w]; wsum[w] = run; run += t; }
                int segfirst = (b >= 61) ? 61 : (b >= 49) ? 49 : 0;
                int pfx = 0;
                if (b != segfirst) {
                    unsigned int f;
                    do {
                        f = __hip_atomic_load(&a.flag[b - 1], __ATOMIC_ACQUIRE,
                                              __HIP_MEMORY_SCOPE_AGENT);
                    } while (f == 0);
                    pfx = (int)(f - 1u);
                }
                __hip_atomic_store(&a.flag[b], (unsigned int)(pfx + run) + 1u,
                                   __ATOMIC_RELEASE, __HIP_MEMORY_SCOPE_AGENT);
                sprefix = pfx;
            }
            __syncthreads();
            if (tid < 256) {
                int add = sprefix + wsum[wid] + incl - tot;
                v.x = add; v.y = add + t0; v.z = add + t01; v.w = add + t012;
                *(int4*)(a.cur + b * 1024 + tid * 4) = v;
            }
        }
    }
    if constexpr (COOP) cooperative_groups::this_grid().sync();

    // P3: fill (cur becomes INCLUSIVE offsets)
    if (PHASE < 0 || PHASE == 3) {
        for (long e = gtid; e < a.Etot; e += nth) {
            int base, d, s, ib;
            if (e < a.E0)       { base = SEG0; d = a.d0[e];         s = a.s0[e];         ib = 0; }
            else if (e < a.E01) { base = SEG1; d = a.d1[e - a.E0];  s = a.s1[e - a.E0];  ib = a.E0; }
            else                { base = SEG2; d = a.d2[e - a.E01]; s = a.s2[e - a.E01]; ib = a.E01; }
            int p = atomicAdd(&a.cur[base + d], 1);
            a.idxa[ib + p] = s;
        }
    }
    if constexpr (COOP) cooperative_groups::this_grid().sync();

    // layer 0
    if (PHASE < 0 || PHASE == 4)
        gather_phase<1>(a.x, a.idxa, a.cur + SEG0, a.meanb, 50000, nb, tid);
    if constexpr (COOP) cooperative_groups::this_grid().sync();
    if (PHASE < 0 || PHASE == 5)
        gemm_phase<0, 1>(a.x, a.meanb, a.wt, a.wt + 65536, a.bias0, a.h1b,
                         50000, nb, tid, As, Bs);
    if constexpr (COOP) cooperative_groups::this_grid().sync();

    // layer 1
    if (PHASE < 0 || PHASE == 6)
        gather_phase<0>(a.h1b, a.idxa + a.E0, a.cur + SEG1, a.meanb, 12000, nb, tid);
    if constexpr (COOP) cooperative_groups::this_grid().sync();
    if (PHASE < 0 || PHASE == 7)
        gemm_phase<0, 0>(a.h1b, a.meanb, a.wt + 2 * 65536, a.wt + 3 * 65536,
                         a.bias1, a.h2b, 12000, nb, tid, As, Bs);
    if constexpr (COOP) cooperative_groups::this_grid().sync();

    // layer 2
    if (PHASE < 0 || PHASE == 8)
        gather_phase<0>(a.h2b, a.idxa + a.E01, a.cur + SEG2, a.meanb, 4000, nb, tid);
    if constexpr (COOP) cooperative_groups::this_grid().sync();
    if (PHASE < 0 || PHASE == 9)
        gemm_phase<1, 0>(a.h2b, a.meanb, a.wt + 4 * 65536, a.wt + 5 * 65536,
                         a.bias2, a.out, 4000, nb, tid, As, Bs);
}

extern "C" void kernel_launch(void* const* d_in, const int* in_sizes, int n_in,
                              void* d_out, int out_size, void* d_ws, size_t ws_size,
                              hipStream_t stream) {
    MegaArgs a;
    a.x = (const float*)d_in[0];
    a.w[0] = (const float*)d_in[1]; a.w[1] = (const float*)d_in[2];
    a.bias0 = (const float*)d_in[3];
    a.w[2] = (const float*)d_in[4]; a.w[3] = (const float*)d_in[5];
    a.bias1 = (const float*)d_in[6];
    a.w[4] = (const float*)d_in[7]; a.w[5] = (const float*)d_in[8];
    a.bias2 = (const float*)d_in[9];
    a.s0 = (const int*)d_in[10]; a.d0 = (const int*)d_in[11];
    a.s1 = (const int*)d_in[12]; a.d1 = (const int*)d_in[13];
    a.s2 = (const int*)d_in[14]; a.d2 = (const int*)d_in[15];
    a.E0 = in_sizes[10];
    a.E01 = a.E0 + in_sizes[12];
    a.Etot = a.E01 + in_sizes[14];
    a.out = (float*)d_out;

    a.h1b   = (unsigned short*)d_ws;                 // 50000*256
    a.h2b   = a.h1b + (size_t)50000 * D;             // 12000*256
    a.meanb = a.h2b + (size_t)12000 * D;             // 50000*256
    a.wt    = a.meanb + (size_t)50000 * D;           // 6*65536 permuted
    a.cur   = (int*)(a.wt + 6 * 65536);              // CURTOT
    a.flag  = (unsigned int*)(a.cur + CURTOT);       // 65 (pad 80)
    a.idxa  = (int*)(a.flag + 80);                   // Etot

    int occ = 0;
    hipError_t oe = hipOccupancyMaxActiveBlocksPerMultiprocessor(&occ, mega<1, -1>, NT, 0);
    int grid = (oe == hipSuccess && occ > 0) ? occ * 256 : 0;

    bool done = false;
    if (grid >= NBLK) {
        void* kargs[] = { (void*)&a };
        hipError_t le = hipLaunchCooperativeKernel(
            reinterpret_cast<void*>(mega<1, -1>), dim3(grid), dim3(NT), kargs, 0, stream);
        done = (le == hipSuccess);
    }
    if (!done) {
        // fallback: same phase bodies as 10 plain launches
        mega<0, 0><<<1536, NT, 0, stream>>>(a);
        mega<0, 1><<<(a.Etot + NT - 1) / NT, NT, 0, stream>>>(a);
        mega<0, 2><<<NBLK, NT, 0, stream>>>(a);
        mega<0, 3><<<(a.Etot + NT - 1) / NT, NT, 0, stream>>>(a);
        mega<0, 4><<<6250, NT, 0, stream>>>(a);
        mega<0, 5><<<391, NT, 0, stream>>>(a);
        mega<0, 6><<<1500, NT, 0, stream>>>(a);
        mega<0, 7><<<94, NT, 0, stream>>>(a);
        mega<0, 8><<<500, NT, 0, stream>>>(a);
        mega<0, 9><<<32, NT, 0, stream>>>(a);
    }
}